// Round 4
// baseline (239.930 us; speedup 1.0000x reference)
//
#include <hip/hip_runtime.h>

#define IMG_W 1024
#define IMG_H 1024
#define BATCH 32
#define STRIP 32              // rows per block
#define CHUNK 4               // rows computed per inner iteration
#define NGROUP (STRIP / CHUNK)

typedef float vfloat4 __attribute__((ext_vector_type(4)));

__device__ __forceinline__ void load_row(const float* __restrict__ img, int ry,
                                         int c0, float* dst) {
    if (ry >= 0 && ry < IMG_H) {
        const float* p = img + (size_t)ry * IMG_W + c0;
        const vfloat4 v = *(const vfloat4*)p;
        dst[1] = v.x; dst[2] = v.y; dst[3] = v.z; dst[4] = v.w;
        dst[0] = (c0 > 0)         ? p[-1] : 0.f;
        dst[5] = (c0 + 4 < IMG_W) ? p[4]  : 0.f;
    } else {
        dst[0] = dst[1] = dst[2] = dst[3] = dst[4] = dst[5] = 0.f;
    }
}

__global__ __launch_bounds__(256) void conv3x3_kernel(
    const float* __restrict__ X,
    const float* __restrict__ wt,
    float* __restrict__ out)
{
    const int y0 = blockIdx.x * STRIP;     // first output row of this strip
    const int b  = blockIdx.y;             // batch
    const int c0 = threadIdx.x * 4;        // first of 4 output cols

    const float* img = X + (size_t)b * IMG_H * IMG_W;

    const float w0 = wt[0], w1 = wt[1], w2 = wt[2];
    const float w3 = wt[3], w4 = wt[4], w5 = wt[5];
    const float w6 = wt[6], w7 = wt[7], w8 = wt[8];

    // Rolling window: W[i] = input row (base-1+i), cols c0-1..c0+4.
    // N[] = prefetch buffer for the next chunk's 4 rows.
    float W[CHUNK + 2][6];
    float N[CHUNK][6];

#pragma unroll
    for (int i = 0; i < CHUNK + 2; ++i)
        load_row(img, y0 - 1 + i, c0, W[i]);

    float* obase = out + ((size_t)b * IMG_H + y0) * IMG_W + c0;

#pragma unroll 1
    for (int g = 0; g < NGROUP; ++g) {
        // Prefetch next chunk's rows (issued before the compute; the
        // dependent use is only at the window-shift below, so the 12 FMA
        // rows of compute overlap the loads).
        if (g + 1 < NGROUP) {
#pragma unroll
            for (int i = 0; i < CHUNK; ++i)
                load_row(img, y0 + (g + 1) * CHUNK + 1 + i, c0, N[i]);
        }

        // Compute + store current chunk from the window.
#pragma unroll
        for (int i = 0; i < CHUNK; ++i) {
            vfloat4 r;
#pragma unroll
            for (int j = 0; j < 4; ++j) {
                r[j] = w0 * W[i][j]     + w1 * W[i][j + 1]     + w2 * W[i][j + 2]
                     + w3 * W[i + 1][j] + w4 * W[i + 1][j + 1] + w5 * W[i + 1][j + 2]
                     + w6 * W[i + 2][j] + w7 * W[i + 2][j + 1] + w8 * W[i + 2][j + 2];
            }
            __builtin_nontemporal_store(r, (vfloat4*)(obase + (size_t)(g * CHUNK + i) * IMG_W));
        }

        // Shift window: last 2 rows carry over, prefetched rows slide in.
#pragma unroll
        for (int k = 0; k < 6; ++k) {
            W[0][k] = W[CHUNK][k];
            W[1][k] = W[CHUNK + 1][k];
        }
#pragma unroll
        for (int i = 0; i < CHUNK; ++i)
#pragma unroll
            for (int k = 0; k < 6; ++k)
                W[2 + i][k] = N[i][k];
    }
}

extern "C" void kernel_launch(void* const* d_in, const int* in_sizes, int n_in,
                              void* d_out, int out_size, void* d_ws, size_t ws_size,
                              hipStream_t stream) {
    const float* X  = (const float*)d_in[0];
    const float* wt = (const float*)d_in[1];
    float* out = (float*)d_out;

    dim3 grid(IMG_H / STRIP, BATCH);  // 32 x 32 = 1024 blocks
    dim3 block(256);                  // 256 threads * 4 cols = 1024 cols
    conv3x3_kernel<<<grid, block, 0, stream>>>(X, wt, out);
}